// Round 5
// baseline (575.312 us; speedup 1.0000x reference)
//
#include <hip/hip_runtime.h>
#include <cstdint>
#include <math.h>

#define HW    3136
#define NPIX  100352      // 32*3136
#define NELEM 25690112    // 32*256*3136

// ---- workspace layout (byte offsets) ----
#define OFF_PW1   0u           // (unused now)
#define OFF_PW2   73728u       // 256*8 u32   = 8192
#define OFF_CORR  81920u       // (unused now)
#define OFF_SC1   86016u
#define OFF_SC2   87040u
#define OFF_A1    88064u
#define OFF_B1    89088u
#define OFF_A2    90112u
#define OFF_B2    91136u
#define OFF_ST    92160u       // st1: 256ch*64slot*2 ull = 262144 ; st2 follows
#define ST_BYTES  524288u
#define OFF_P1    616448u      // now: W fragments i8, 36*16*64*16 = 589824 B
#define OFF_P2    3827712u     // p2 bitplanes (conv2 path, unchanged)
#define OFF_S1    7038976u     // NELEM i16 (tiled) = 51380224
#define OFF_S2    58419200u    // NELEM i16 (tiled); ALSO aliased as act_i8
                               // (25.7MB) which is dead before conv2 writes S2

typedef int i32x4 __attribute__((ext_vector_type(4)));

// ============ weight prep: scales + conv2 bit-packing ============
__global__ __launch_bounds__(256) void prep_w_k(const float* __restrict__ w3,
                         const float* __restrict__ wr,
                         uint32_t* __restrict__ pw2,
                         float* __restrict__ sc1, float* __restrict__ sc2) {
  __shared__ float s1S[4], s2S[4];
  const int o = blockIdx.x;
  const int tid = threadIdx.x;
  const int l = tid & 63, wv = tid >> 6;
  const float* wo = w3 + (size_t)o * 2304 + (size_t)tid * 9;
  float s = 0.f;
#pragma unroll
  for (int t = 0; t < 9; ++t) s += fabsf(wo[t]);
#pragma unroll
  for (int m = 32; m; m >>= 1) s += __shfl_xor(s, m, 64);
  float v2 = wr[(size_t)o * 256 + tid];
  float s2 = fabsf(v2);
#pragma unroll
  for (int m = 32; m; m >>= 1) s2 += __shfl_xor(s2, m, 64);
  unsigned long long mb2 = __ballot(v2 >= 0.0f);
  if (l == 0) {
    pw2[(size_t)o * 8 + wv * 2 + 0] = (uint32_t)mb2;
    pw2[(size_t)o * 8 + wv * 2 + 1] = (uint32_t)(mb2 >> 32);
    s1S[wv] = s; s2S[wv] = s2;
  }
  __syncthreads();
  if (tid == 0) {
    sc1[o] = (s1S[0] + s1S[1] + s1S[2] + s1S[3]) / 2304.0f;
    sc2[o] = (s2S[0] + s2S[1] + s2S[2] + s2S[3]) / 256.0f;
  }
}

// ============ W fragments for i8 MFMA: [s 36][t 16][lane 64][16 i8] ============
// B(64x16) fragment: col = lane&15 (och in tile), k' = (lane>>4)*16 + i,
// global k = s*64 + k' = tap*256 + ch  (tap = s>>2, ch = (s&3)*64 + k').
__global__ void prep_wfrag_k(const float* __restrict__ w3, char* __restrict__ wf) {
  const int s = blockIdx.x, t = blockIdx.y;
  const int l = threadIdx.x;             // 64 threads = 1 wave
  const int och = t * 16 + (l & 15), lg = l >> 4;
  const int tap = s >> 2;
  const int chb = (s & 3) * 64 + lg * 16;
  const float* wp = w3 + (size_t)och * 2304 + tap;
  uint32_t wd[4];
#pragma unroll
  for (int u = 0; u < 4; ++u) {
    uint32_t v = 0;
#pragma unroll
    for (int i = 0; i < 4; ++i) {
      float x = wp[(size_t)(chb + u * 4 + i) * 9];
      uint32_t b = (x >= 0.f) ? 0x01u : 0xFFu;
      v |= b << (8 * i);
    }
    wd[u] = v;
  }
  uint4 o; o.x = wd[0]; o.y = wd[1]; o.z = wd[2]; o.w = wd[3];
  *(uint4*)&wf[((size_t)(s * 16 + t) * 64 + l) * 16] = o;
}

// ============ pack_act: sign(x + b1_1) -> i8 +-1, layout [n][px][ch] ============
__global__ __launch_bounds__(256) void pack_act_k(const float* __restrict__ x,
                                                  const float* __restrict__ b1_1,
                                                  char* __restrict__ act) {
  const int gid = blockIdx.x * 256 + threadIdx.x;   // 200704 = 2 * NPIX
  const int pxid = gid >> 1, half = gid & 1;
  const int n = pxid / 3136, p = pxid - n * 3136;
  const float* xb = x + ((size_t)n * 256 + half * 128) * 3136 + p;
  const float* bb = b1_1 + half * 128;
  uint32_t w[32];
#pragma unroll
  for (int cc = 0; cc < 128; ++cc) {
    float v = xb[(size_t)cc * 3136] + bb[cc];
    uint32_t b = (v >= 0.f) ? 0x01u : 0xFFu;
    if ((cc & 3) == 0) w[cc >> 2] = b;
    else               w[cc >> 2] |= b << ((cc & 3) * 8);
  }
  uint4* dst = (uint4*)&act[(size_t)pxid * 256 + half * 128];
#pragma unroll
  for (int u = 0; u < 8; ++u) {
    uint4 o; o.x = w[u*4]; o.y = w[u*4+1]; o.z = w[u*4+2]; o.w = w[u*4+3];
    dst[u] = o;
  }
}

// ============ conv1: 3x3 binarized as i8 implicit GEMM on MFMA ============
// block 256 thr = 4 waves; 8x8 px tile (halo 10x10 zero-stuffed), 256 och.
// Per wave: 4 M-tiles x 4 och-tiles (och = wv*64..), K = 2304 in 36 steps of 64.
// A from LDS act (XOR-swizzled 16B chunks), B from LDS W double-buffer
// (T14 issue-early/write-late streaming from L2). C/D layout per m89:
// col=lane&15, row=(lane>>4)*4+reg. Zero halo == reference zero padding,
// so no edge corrections needed; integer S identical to XNOR formulation.
__global__ __launch_bounds__(256, 2) void conv1_k(const char* __restrict__ act,
    const char* __restrict__ wf, short* __restrict__ S1,
    unsigned long long* __restrict__ st1) {
  __shared__ __align__(16) char actS[25600];     // 100 cells x 256 ch
  __shared__ __align__(16) char wS[2][16384];    // 16 och-tiles x 64 lanes x 16
  const int tid = threadIdx.x;
  const int bx = blockIdx.x, n = blockIdx.y;
  const int ty = bx / 7, tx = bx % 7;
  const int lane = tid & 63, wv = tid >> 6;
  const int h0 = ty * 8 - 1, w0 = tx * 8 - 1;
  const char* actB = act + (size_t)n * 3136 * 256;
  for (int i = tid; i < 1600; i += 256) {
    int cell = i >> 4, ck = i & 15;
    int r = cell / 10, c = cell - r * 10;
    int hh = h0 + r, ww = w0 + c;
    uint4 v; v.x = 0; v.y = 0; v.z = 0; v.w = 0;
    if ((unsigned)hh < 56u && (unsigned)ww < 56u)
      v = *(const uint4*)(actB + (size_t)(hh * 56 + ww) * 256 + ck * 16);
    *(uint4*)&actS[cell * 256 + (ck ^ (cell & 7)) * 16] = v;
  }
  uint4 wreg[4];
  {
    const uint4* src = (const uint4*)wf;
#pragma unroll
    for (int u = 0; u < 4; ++u) wreg[u] = src[tid * 4 + u];
    uint4* dst = (uint4*)&wS[0][0];
#pragma unroll
    for (int u = 0; u < 4; ++u) dst[tid * 4 + u] = wreg[u];
  }
  __syncthreads();

  i32x4 C[4][4];
#pragma unroll
  for (int m = 0; m < 4; ++m)
#pragma unroll
    for (int tt = 0; tt < 4; ++tt) C[m][tt] = (i32x4){0, 0, 0, 0};

#pragma unroll 1
  for (int s = 0; s < 36; ++s) {
    const int b = s & 1;
    if (s < 35) {                                  // issue next W loads early
      const uint4* src = (const uint4*)(wf + (size_t)(s + 1) * 16384);
#pragma unroll
      for (int u = 0; u < 4; ++u) wreg[u] = src[tid * 4 + u];
    }
    const int tap = s >> 2, chq = s & 3;
    const int dh = tap / 3, dw = tap - dh * 3;
    i32x4 Af[4];
#pragma unroll
    for (int m = 0; m < 4; ++m) {
      int pxl = m * 16 + (lane & 15);
      int cell = ((pxl >> 3) + dh) * 10 + (pxl & 7) + dw;
      int ck = (chq * 4 + (lane >> 4)) ^ (cell & 7);
      Af[m] = *(const i32x4*)&actS[cell * 256 + ck * 16];
    }
    i32x4 Bf[4];
#pragma unroll
    for (int tt = 0; tt < 4; ++tt)
      Bf[tt] = *(const i32x4*)&wS[b][((wv * 4 + tt) * 64 + lane) * 16];
#pragma unroll
    for (int m = 0; m < 4; ++m)
#pragma unroll
      for (int tt = 0; tt < 4; ++tt)
        C[m][tt] = __builtin_amdgcn_mfma_i32_16x16x64_i8(Af[m], Bf[tt], C[m][tt], 0, 0, 0);
    if (s < 35) {                                  // write-late into other buf
      uint4* dst = (uint4*)&wS[b ^ 1][0];
#pragma unroll
      for (int u = 0; u < 4; ++u) dst[tid * 4 + u] = wreg[u];
    }
    __syncthreads();
  }

  const int slot = (bx + n * 49) & 63;
  const size_t s1base = ((size_t)n * 49 + bx) * 256;
#pragma unroll
  for (int tt = 0; tt < 4; ++tt) {
    const int och = (wv * 4 + tt) * 16 + (lane & 15);
    int sm = 0, sq = 0;
#pragma unroll
    for (int m = 0; m < 4; ++m) {
      i32x4 v = C[m][tt];
      short4 o4;
      o4.x = (short)v.x; o4.y = (short)v.y; o4.z = (short)v.z; o4.w = (short)v.w;
      *(short4*)&S1[(s1base + och) * 64 + m * 16 + (lane >> 4) * 4] = o4;
      sm += v.x + v.y + v.z + v.w;
      sq += v.x * v.x + v.y * v.y + v.z * v.z + v.w * v.w;
    }
    sm += __shfl_xor(sm, 16, 64); sm += __shfl_xor(sm, 32, 64);
    sq += __shfl_xor(sq, 16, 64); sq += __shfl_xor(sq, 32, 64);
    if (lane < 16) {
      unsigned long long* st = st1 + ((size_t)och * 64 + slot) * 2;
      atomicAdd(&st[0], (unsigned long long)(long long)sm);
      atomicAdd(&st[1], (unsigned long long)(long long)sq);
    }
  }
}

// ============ BN finalize (parallel): fold to y = A*S + B ============
__global__ void bnfin_k(const unsigned long long* __restrict__ st, const float* __restrict__ sc,
                        const float* __restrict__ g, const float* __restrict__ b,
                        float* __restrict__ A, float* __restrict__ B) {
  const int c = blockIdx.x, l = threadIdx.x;
  long long sm = (long long)st[((size_t)c * 64 + l) * 2 + 0];
  long long sq = (long long)st[((size_t)c * 64 + l) * 2 + 1];
  for (int m = 1; m < 64; m <<= 1) { sm += __shfl_xor(sm, m, 64); sq += __shfl_xor(sq, m, 64); }
  if (l == 0) {
    const double M = (double)NPIX;
    double mS = (double)sm / M;
    double vS = (double)sq / M - mS * mS;
    double scale = (double)sc[c];
    double mean = scale * mS;
    double var = scale * scale * vS;
    double rstd = 1.0 / sqrt(var + 1e-5);
    double gd = (double)g[c];
    A[c] = (float)(gd * scale * rstd);
    B[c] = (float)((double)b[c] - gd * mean * rstd);
  }
}

// ============ pack2: elementwise chain -> sign bits, float4-vectorized ============
__global__ __launch_bounds__(256) void pack2_k(const float* __restrict__ x,
    const short* __restrict__ S1,
    const float* __restrict__ A1, const float* __restrict__ B1,
    const float* __restrict__ b1_2, const float* __restrict__ a1,
    const float* __restrict__ b1_3, const float* __restrict__ b2_1,
    uint32_t* __restrict__ p2) {
  const int j = blockIdx.y;
  const int gpx = blockIdx.x * 256 + threadIdx.x;
  const int n = gpx / 784;
  const int p4 = (gpx - n * 784) * 4;
  const int h = p4 / 56, w = p4 - (p4 / 56) * 56;
  const int tile = (h >> 3) * 7 + (w >> 3);
  const int px = (h & 7) * 8 + (w & 7);
  const float* xb = x + ((size_t)n * 256 + j * 32) * HW + p4;
  const short* s1b = S1 + (((size_t)n * 49 + tile) * 256 + j * 32) * 64 + px;
  uint32_t w0 = 0, w1 = 0, w2 = 0, w3 = 0;
#pragma unroll
  for (int cc = 0; cc < 32; ++cc) {
    int c = j * 32 + cc;
    float4 xv = *(const float4*)(xb + (size_t)cc * HW);
    short4 s1 = *(const short4*)(s1b + cc * 64);
    float Ac = A1[c], Bc = B1[c], p12 = b1_2[c], al = a1[c], p13 = b1_3[c], p21 = b2_1[c];
    float u, v, t;
    u = xv.x + (Ac * (float)s1.x + Bc) + p12; v = u >= 0.f ? u : al * u; t = v + p13 + p21;
    w0 |= (t >= 0.f) ? (1u << cc) : 0u;
    u = xv.y + (Ac * (float)s1.y + Bc) + p12; v = u >= 0.f ? u : al * u; t = v + p13 + p21;
    w1 |= (t >= 0.f) ? (1u << cc) : 0u;
    u = xv.z + (Ac * (float)s1.z + Bc) + p12; v = u >= 0.f ? u : al * u; t = v + p13 + p21;
    w2 |= (t >= 0.f) ? (1u << cc) : 0u;
    u = xv.w + (Ac * (float)s1.w + Bc) + p12; v = u >= 0.f ? u : al * u; t = v + p13 + p21;
    w3 |= (t >= 0.f) ? (1u << cc) : 0u;
  }
  uint4 o = {w0, w1, w2, w3};
  *(uint4*)&p2[(size_t)j * NPIX + gpx * 4] = o;
}

// ============ conv2: 1x1 binarized, swizzled act, interleaved channels ============
__global__ __launch_bounds__(256) void conv2_k(const uint32_t* __restrict__ p2,
                                               const uint32_t* __restrict__ pw2,
                                               short* __restrict__ S2,
                                               unsigned long long* __restrict__ st2) {
  __shared__ __align__(16) uint32_t actS[512];   // 64 px x 8 q, XOR-swizzled 16B groups
  __shared__ __align__(16) uint32_t wtS[1024];   // [ch_l 128][q 8]
  const int tid = threadIdx.x;
  const int bx = blockIdx.x;       // 0..1567 pixel group
  const int zh = blockIdx.y;
  const int pg0 = bx * 64;
  for (int i = tid; i < 512; i += 256) {
    int gq = i >> 2, ws_ = i & 3;
    int pxl = gq >> 1, q4 = gq & 1;
    int q = q4 * 4 + ws_;
    actS[((gq ^ ((gq >> 3) & 15)) << 2) + ws_] = p2[q * NPIX + pg0 + pxl];
  }
  if (tid < 256)
    ((uint4*)wtS)[tid] = ((const uint4*)(pw2 + zh * 1024))[tid];
  __syncthreads();
  const int pxg = tid & 15, chg = tid >> 4;
  int acc[8][4];
#pragma unroll
  for (int j = 0; j < 8; ++j)
#pragma unroll
    for (int k = 0; k < 4; ++k) acc[j][k] = 0;
#pragma unroll
  for (int q4 = 0; q4 < 2; ++q4) {
    uint4 a[4];
#pragma unroll
    for (int k = 0; k < 4; ++k) {
      int gq = 8 * pxg + 2 * k + q4;
      a[k] = *(const uint4*)&actS[(gq ^ pxg) << 2];
    }
#pragma unroll
    for (int j = 0; j < 8; ++j) {
      uint4 w = *(const uint4*)&wtS[(chg + 16 * j) * 8 + q4 * 4];
#pragma unroll
      for (int k = 0; k < 4; ++k) {
        int t = acc[j][k];
        t += __builtin_popcount(a[k].x ^ w.x);
        t += __builtin_popcount(a[k].y ^ w.y);
        t += __builtin_popcount(a[k].z ^ w.z);
        t += __builtin_popcount(a[k].w ^ w.w);
        acc[j][k] = t;
      }
    }
  }
  const int slot = bx & 63;
#pragma unroll
  for (int j = 0; j < 8; ++j) {
    const int c_l = chg + 16 * j;
    int s[4], sm = 0, sq = 0;
#pragma unroll
    for (int k = 0; k < 4; ++k) {
      s[k] = 256 - 2 * acc[j][k];
      sm += s[k]; sq += s[k] * s[k];
    }
    short4 o4;
    o4.x = (short)s[0]; o4.y = (short)s[1]; o4.z = (short)s[2]; o4.w = (short)s[3];
    *(short4*)&S2[(((size_t)bx * 256) + zh * 128 + c_l) * 64 + pxg * 4] = o4;
#pragma unroll
    for (int m = 1; m < 16; m <<= 1) { sm += __shfl_xor(sm, m, 64); sq += __shfl_xor(sq, m, 64); }
    if (pxg == 0) {
      unsigned long long* st = st2 + ((size_t)(zh * 128 + c_l) * 64 + slot) * 2;
      atomicAdd(&st[0], (unsigned long long)(long long)sm);
      atomicAdd(&st[1], (unsigned long long)(long long)sq);
    }
  }
}

// ============ final: recompute t, BN2 + residual + PReLU chain ============
__global__ __launch_bounds__(256) void final_k(const float* __restrict__ x,
    const short* __restrict__ S1, const short* __restrict__ S2,
    const float* __restrict__ A1, const float* __restrict__ B1,
    const float* __restrict__ b1_2, const float* __restrict__ a1, const float* __restrict__ b1_3,
    const float* __restrict__ A2, const float* __restrict__ B2,
    const float* __restrict__ b2_2, const float* __restrict__ a2, const float* __restrict__ b2_3,
    float* __restrict__ out) {
  const int gi = blockIdx.x * 256 + threadIdx.x;
  const int i4 = gi * 4;
  const int nc = i4 / 3136;
  const int p = i4 - nc * 3136;
  const int n = nc >> 8, c = nc & 255;
  const int h = p / 56, w = p - (p / 56) * 56;
  const int tile = (h >> 3) * 7 + (w >> 3);
  const int px = (h & 7) * 8 + (w & 7);
  short4 s1 = *(const short4*)&S1[(((size_t)n * 49 + tile) * 256 + c) * 64 + px];
  const int pg = n * 3136 + p;
  short4 s2 = *(const short4*)&S2[((size_t)(pg >> 6) * 256 + c) * 64 + (pg & 63)];
  float4 xv = *(const float4*)&x[i4];
  const float A1c = A1[c], B1c = B1[c], P12 = b1_2[c], AL1 = a1[c], P13 = b1_3[c];
  const float A2c = A2[c], B2c = B2[c], P22 = b2_2[c], AL2 = a2[c], P23 = b2_3[c];
  float xs[4] = {xv.x, xv.y, xv.z, xv.w};
  float f1[4] = {(float)s1.x, (float)s1.y, (float)s1.z, (float)s1.w};
  float f2[4] = {(float)s2.x, (float)s2.y, (float)s2.z, (float)s2.w};
  float o[4];
#pragma unroll
  for (int e = 0; e < 4; ++e) {
    float u = xs[e] + (A1c * f1[e] + B1c);
    u = u + P12;
    float v = u >= 0.0f ? u : AL1 * u;
    float t = v + P13;
    float z = (A2c * f2[e] + B2c) + t;
    z = z + P22;
    float vv = z >= 0.0f ? z : AL2 * z;
    o[e] = vv + P23;
  }
  float4 ov = {o[0], o[1], o[2], o[3]};
  *(float4*)&out[i4] = ov;
}

extern "C" void kernel_launch(void* const* d_in, const int* in_sizes, int n_in,
                              void* d_out, int out_size, void* d_ws, size_t ws_size,
                              hipStream_t stream) {
  const float* x    = (const float*)d_in[0];
  const float* b1_1 = (const float*)d_in[1];
  const float* w3x3 = (const float*)d_in[2];
  const float* bn1g = (const float*)d_in[3];
  const float* bn1b = (const float*)d_in[4];
  const float* b1_2 = (const float*)d_in[5];
  const float* a1   = (const float*)d_in[6];
  const float* b1_3 = (const float*)d_in[7];
  const float* b2_1 = (const float*)d_in[8];
  const float* wres = (const float*)d_in[9];
  const float* bn2g = (const float*)d_in[10];
  const float* bn2b = (const float*)d_in[11];
  const float* b2_2 = (const float*)d_in[12];
  const float* a2   = (const float*)d_in[13];
  const float* b2_3 = (const float*)d_in[14];

  char* ws = (char*)d_ws;
  uint32_t* pw2 = (uint32_t*)(ws + OFF_PW2);
  float* sc1 = (float*)(ws + OFF_SC1);
  float* sc2 = (float*)(ws + OFF_SC2);
  float* A1 = (float*)(ws + OFF_A1);
  float* B1 = (float*)(ws + OFF_B1);
  float* A2 = (float*)(ws + OFF_A2);
  float* B2 = (float*)(ws + OFF_B2);
  unsigned long long* st1 = (unsigned long long*)(ws + OFF_ST);
  unsigned long long* st2 = (unsigned long long*)(ws + OFF_ST + 262144u);
  char* wf  = (char*)(ws + OFF_P1);       // W fragments (590KB) in old p1 slot
  uint32_t* p2 = (uint32_t*)(ws + OFF_P2);
  short* S1 = (short*)(ws + OFF_S1);
  short* S2 = (short*)(ws + OFF_S2);
  char* act = (char*)(ws + OFF_S2);       // act_i8 aliases S2 (dead before conv2)

  hipMemsetAsync(ws + OFF_ST, 0, ST_BYTES, stream);
  prep_w_k<<<256, 256, 0, stream>>>(w3x3, wres, pw2, sc1, sc2);
  prep_wfrag_k<<<dim3(36, 16), 64, 0, stream>>>(w3x3, wf);
  pack_act_k<<<784, 256, 0, stream>>>(x, b1_1, act);
  conv1_k<<<dim3(49, 32), 256, 0, stream>>>(act, wf, S1, st1);
  bnfin_k<<<256, 64, 0, stream>>>(st1, sc1, bn1g, bn1b, A1, B1);
  pack2_k<<<dim3(98, 8), 256, 0, stream>>>(x, S1, A1, B1, b1_2, a1, b1_3, b2_1, p2);
  conv2_k<<<dim3(1568, 2), 256, 0, stream>>>(p2, pw2, S2, st2);
  bnfin_k<<<256, 64, 0, stream>>>(st2, sc2, bn2g, bn2b, A2, B2);
  final_k<<<25088, 256, 0, stream>>>(x, S1, S2, A1, B1, b1_2, a1, b1_3,
                                     A2, B2, b2_2, a2, b2_3, (float*)d_out);
}

// Round 6
// 450.376 us; speedup vs baseline: 1.2774x; 1.2774x over previous
//
#include <hip/hip_runtime.h>
#include <cstdint>
#include <math.h>

#define HW    3136
#define NPIX  100352      // 32*3136
#define NELEM 25690112    // 32*256*3136

// ---- workspace layout (byte offsets) ----
#define OFF_PW2   73728u       // 256*8 u32   = 8192
#define OFF_SC1   86016u
#define OFF_SC2   87040u
#define OFF_A1    88064u
#define OFF_B1    89088u
#define OFF_A2    90112u
#define OFF_B2    91136u
#define OFF_ST    92160u       // st1: 256ch*64slot*2 ull = 262144 ; st2 follows
#define ST_BYTES  524288u
#define OFF_P1    616448u      // W fragments i8, 36*16*64*16 = 589824 B
#define OFF_P2    3827712u     // p2 bitplanes (conv2 path)
#define OFF_S1    7038976u     // NELEM i16 (tiled) = 51380224
#define OFF_S2    58419200u    // NELEM i16 (tiled); aliased as act_i8 pre-conv2

typedef int i32x4 __attribute__((ext_vector_type(4)));

// ============ weight prep: scales + conv2 bit-packing ============
__global__ __launch_bounds__(256) void prep_w_k(const float* __restrict__ w3,
                         const float* __restrict__ wr,
                         uint32_t* __restrict__ pw2,
                         float* __restrict__ sc1, float* __restrict__ sc2) {
  __shared__ float s1S[4], s2S[4];
  const int o = blockIdx.x;
  const int tid = threadIdx.x;
  const int l = tid & 63, wv = tid >> 6;
  const float* wo = w3 + (size_t)o * 2304 + (size_t)tid * 9;
  float s = 0.f;
#pragma unroll
  for (int t = 0; t < 9; ++t) s += fabsf(wo[t]);
#pragma unroll
  for (int m = 32; m; m >>= 1) s += __shfl_xor(s, m, 64);
  float v2 = wr[(size_t)o * 256 + tid];
  float s2 = fabsf(v2);
#pragma unroll
  for (int m = 32; m; m >>= 1) s2 += __shfl_xor(s2, m, 64);
  unsigned long long mb2 = __ballot(v2 >= 0.0f);
  if (l == 0) {
    pw2[(size_t)o * 8 + wv * 2 + 0] = (uint32_t)mb2;
    pw2[(size_t)o * 8 + wv * 2 + 1] = (uint32_t)(mb2 >> 32);
    s1S[wv] = s; s2S[wv] = s2;
  }
  __syncthreads();
  if (tid == 0) {
    sc1[o] = (s1S[0] + s1S[1] + s1S[2] + s1S[3]) / 2304.0f;
    sc2[o] = (s2S[0] + s2S[1] + s2S[2] + s2S[3]) / 256.0f;
  }
}

// ============ W fragments for i8 MFMA: [s 36][t 16][lane 64][16 i8] ============
__global__ void prep_wfrag_k(const float* __restrict__ w3, char* __restrict__ wf) {
  const int s = blockIdx.x, t = blockIdx.y;
  const int l = threadIdx.x;             // 64 threads = 1 wave
  const int och = t * 16 + (l & 15), lg = l >> 4;
  const int tap = s >> 2;
  const int chb = (s & 3) * 64 + lg * 16;
  const float* wp = w3 + (size_t)och * 2304 + tap;
  uint32_t wd[4];
#pragma unroll
  for (int u = 0; u < 4; ++u) {
    uint32_t v = 0;
#pragma unroll
    for (int i = 0; i < 4; ++i) {
      float x = wp[(size_t)(chb + u * 4 + i) * 9];
      uint32_t b = (x >= 0.f) ? 0x01u : 0xFFu;
      v |= b << (8 * i);
    }
    wd[u] = v;
  }
  uint4 o; o.x = wd[0]; o.y = wd[1]; o.z = wd[2]; o.w = wd[3];
  *(uint4*)&wf[((size_t)(s * 16 + t) * 64 + l) * 16] = o;
}

// ============ pack_act: sign(x + b1_1) -> i8 +-1, layout [n][px][ch] ============
__global__ __launch_bounds__(256) void pack_act_k(const float* __restrict__ x,
                                                  const float* __restrict__ b1_1,
                                                  char* __restrict__ act) {
  const int gid = blockIdx.x * 256 + threadIdx.x;   // 200704 = 2 * NPIX
  const int pxid = gid >> 1, half = gid & 1;
  const int n = pxid / 3136, p = pxid - n * 3136;
  const float* xb = x + ((size_t)n * 256 + half * 128) * 3136 + p;
  const float* bb = b1_1 + half * 128;
  uint32_t w[32];
#pragma unroll
  for (int cc = 0; cc < 128; ++cc) {
    float v = xb[(size_t)cc * 3136] + bb[cc];
    uint32_t b = (v >= 0.f) ? 0x01u : 0xFFu;
    if ((cc & 3) == 0) w[cc >> 2] = b;
    else               w[cc >> 2] |= b << ((cc & 3) * 8);
  }
  uint4* dst = (uint4*)&act[(size_t)pxid * 256 + half * 128];
#pragma unroll
  for (int u = 0; u < 8; ++u) {
    uint4 o; o.x = w[u*4]; o.y = w[u*4+1]; o.z = w[u*4+2]; o.w = w[u*4+3];
    dst[u] = o;
  }
}

// ============ conv1: 3x3 binarized as i8 implicit GEMM on MFMA ============
// R5 postmortem: 5.87e7 LDS bank conflicts came from (a) wS dbuf writes at
// 64B thread stride (16-way write conflict) and (b) actS cell stride 256
// (bank = chunk idx only). Fix: NO W LDS at all -- B fragments stream
// L2->VGPR per wave (64lane x 16B contiguous = coalesced), register
// double-buffered; actS cell stride padded to 272B so bank-group =
// (cell+ck)&7 -> staging writes (fixed cell, ck 0..15) AND A-reads
// (consecutive cells, fixed ck) are conflict-free by construction.
// Zero barriers in the K-loop; LDS 27.2KB.
__global__ __launch_bounds__(256) void conv1_k(const char* __restrict__ act,
    const char* __restrict__ wf, short* __restrict__ S1,
    unsigned long long* __restrict__ st1) {
  __shared__ __align__(16) char actS[27200];     // 100 cells x 272B (256 used)
  const int tid = threadIdx.x;
  const int bx = blockIdx.x, n = blockIdx.y;
  const int ty = bx / 7, tx = bx % 7;
  const int lane = tid & 63, wv = tid >> 6;
  const int h0 = ty * 8 - 1, w0 = tx * 8 - 1;
  const char* actB = act + (size_t)n * 3136 * 256;
  for (int i = tid; i < 1600; i += 256) {
    int cell = i >> 4, ck = i & 15;
    int r = cell / 10, c = cell - r * 10;
    int hh = h0 + r, ww = w0 + c;
    uint4 v; v.x = 0; v.y = 0; v.z = 0; v.w = 0;
    if ((unsigned)hh < 56u && (unsigned)ww < 56u)
      v = *(const uint4*)(actB + (size_t)(hh * 56 + ww) * 256 + ck * 16);
    *(uint4*)&actS[cell * 272 + ck * 16] = v;
  }
  __syncthreads();

  const uint4* wfv = (const uint4*)wf;
  const int lg = lane >> 4;
  // per-lane invariant byte offset: (b*10 + col) cells + lane-group chunk
  const int laneOff = (((lane >> 3) & 1) * 10 + (lane & 7)) * 272 + lg * 16;

  i32x4 C[4][4];
#pragma unroll
  for (int m = 0; m < 4; ++m)
#pragma unroll
    for (int tt = 0; tt < 4; ++tt) C[m][tt] = (i32x4){0, 0, 0, 0};

  i32x4 Bc[4];
#pragma unroll
  for (int tt = 0; tt < 4; ++tt)
    Bc[tt] = *(const i32x4*)&wfv[(size_t)((wv * 4 + tt) * 64) + lane];

#pragma unroll 1
  for (int s = 0; s < 36; ++s) {
    i32x4 Bn[4];
    if (s < 35) {
#pragma unroll
      for (int tt = 0; tt < 4; ++tt)
        Bn[tt] = *(const i32x4*)&wfv[(size_t)(((s + 1) * 16 + wv * 4 + tt) * 64) + lane];
    }
    const int tap = s >> 2, chq = s & 3;
    const int dh = tap / 3, dw = tap - dh * 3;
    const int stepOff = (dh * 10 + dw) * 272 + chq * 64 + laneOff;
    i32x4 Af[4];
#pragma unroll
    for (int m = 0; m < 4; ++m)
      Af[m] = *(const i32x4*)&actS[m * 5440 + stepOff];
#pragma unroll
    for (int m = 0; m < 4; ++m)
#pragma unroll
      for (int tt = 0; tt < 4; ++tt)
        C[m][tt] = __builtin_amdgcn_mfma_i32_16x16x64_i8(Af[m], Bc[tt], C[m][tt], 0, 0, 0);
    if (s < 35) {
#pragma unroll
      for (int tt = 0; tt < 4; ++tt) Bc[tt] = Bn[tt];
    }
  }

  const int slot = (bx + n * 49) & 63;
  const size_t s1base = ((size_t)n * 49 + bx) * 256;
#pragma unroll
  for (int tt = 0; tt < 4; ++tt) {
    const int och = (wv * 4 + tt) * 16 + (lane & 15);
    int sm = 0, sq = 0;
#pragma unroll
    for (int m = 0; m < 4; ++m) {
      i32x4 v = C[m][tt];
      short4 o4;
      o4.x = (short)v.x; o4.y = (short)v.y; o4.z = (short)v.z; o4.w = (short)v.w;
      *(short4*)&S1[(s1base + och) * 64 + m * 16 + (lane >> 4) * 4] = o4;
      sm += v.x + v.y + v.z + v.w;
      sq += v.x * v.x + v.y * v.y + v.z * v.z + v.w * v.w;
    }
    sm += __shfl_xor(sm, 16, 64); sm += __shfl_xor(sm, 32, 64);
    sq += __shfl_xor(sq, 16, 64); sq += __shfl_xor(sq, 32, 64);
    if (lane < 16) {
      unsigned long long* st = st1 + ((size_t)och * 64 + slot) * 2;
      atomicAdd(&st[0], (unsigned long long)(long long)sm);
      atomicAdd(&st[1], (unsigned long long)(long long)sq);
    }
  }
}

// ============ BN finalize (parallel): fold to y = A*S + B ============
__global__ void bnfin_k(const unsigned long long* __restrict__ st, const float* __restrict__ sc,
                        const float* __restrict__ g, const float* __restrict__ b,
                        float* __restrict__ A, float* __restrict__ B) {
  const int c = blockIdx.x, l = threadIdx.x;
  long long sm = (long long)st[((size_t)c * 64 + l) * 2 + 0];
  long long sq = (long long)st[((size_t)c * 64 + l) * 2 + 1];
  for (int m = 1; m < 64; m <<= 1) { sm += __shfl_xor(sm, m, 64); sq += __shfl_xor(sq, m, 64); }
  if (l == 0) {
    const double M = (double)NPIX;
    double mS = (double)sm / M;
    double vS = (double)sq / M - mS * mS;
    double scale = (double)sc[c];
    double mean = scale * mS;
    double var = scale * scale * vS;
    double rstd = 1.0 / sqrt(var + 1e-5);
    double gd = (double)g[c];
    A[c] = (float)(gd * scale * rstd);
    B[c] = (float)((double)b[c] - gd * mean * rstd);
  }
}

// ============ pack2: elementwise chain -> sign bits, float4-vectorized ============
__global__ __launch_bounds__(256) void pack2_k(const float* __restrict__ x,
    const short* __restrict__ S1,
    const float* __restrict__ A1, const float* __restrict__ B1,
    const float* __restrict__ b1_2, const float* __restrict__ a1,
    const float* __restrict__ b1_3, const float* __restrict__ b2_1,
    uint32_t* __restrict__ p2) {
  const int j = blockIdx.y;
  const int gpx = blockIdx.x * 256 + threadIdx.x;
  const int n = gpx / 784;
  const int p4 = (gpx - n * 784) * 4;
  const int h = p4 / 56, w = p4 - (p4 / 56) * 56;
  const int tile = (h >> 3) * 7 + (w >> 3);
  const int px = (h & 7) * 8 + (w & 7);
  const float* xb = x + ((size_t)n * 256 + j * 32) * HW + p4;
  const short* s1b = S1 + (((size_t)n * 49 + tile) * 256 + j * 32) * 64 + px;
  uint32_t w0 = 0, w1 = 0, w2 = 0, w3 = 0;
#pragma unroll
  for (int cc = 0; cc < 32; ++cc) {
    int c = j * 32 + cc;
    float4 xv = *(const float4*)(xb + (size_t)cc * HW);
    short4 s1 = *(const short4*)(s1b + cc * 64);
    float Ac = A1[c], Bc = B1[c], p12 = b1_2[c], al = a1[c], p13 = b1_3[c], p21 = b2_1[c];
    float u, v, t;
    u = xv.x + (Ac * (float)s1.x + Bc) + p12; v = u >= 0.f ? u : al * u; t = v + p13 + p21;
    w0 |= (t >= 0.f) ? (1u << cc) : 0u;
    u = xv.y + (Ac * (float)s1.y + Bc) + p12; v = u >= 0.f ? u : al * u; t = v + p13 + p21;
    w1 |= (t >= 0.f) ? (1u << cc) : 0u;
    u = xv.z + (Ac * (float)s1.z + Bc) + p12; v = u >= 0.f ? u : al * u; t = v + p13 + p21;
    w2 |= (t >= 0.f) ? (1u << cc) : 0u;
    u = xv.w + (Ac * (float)s1.w + Bc) + p12; v = u >= 0.f ? u : al * u; t = v + p13 + p21;
    w3 |= (t >= 0.f) ? (1u << cc) : 0u;
  }
  uint4 o = {w0, w1, w2, w3};
  *(uint4*)&p2[(size_t)j * NPIX + gpx * 4] = o;
}

// ============ conv2: 1x1 binarized, swizzled act, interleaved channels ============
__global__ __launch_bounds__(256) void conv2_k(const uint32_t* __restrict__ p2,
                                               const uint32_t* __restrict__ pw2,
                                               short* __restrict__ S2,
                                               unsigned long long* __restrict__ st2) {
  __shared__ __align__(16) uint32_t actS[512];   // 64 px x 8 q, XOR-swizzled 16B groups
  __shared__ __align__(16) uint32_t wtS[1024];   // [ch_l 128][q 8]
  const int tid = threadIdx.x;
  const int bx = blockIdx.x;       // 0..1567 pixel group
  const int zh = blockIdx.y;
  const int pg0 = bx * 64;
  for (int i = tid; i < 512; i += 256) {
    int gq = i >> 2, ws_ = i & 3;
    int pxl = gq >> 1, q4 = gq & 1;
    int q = q4 * 4 + ws_;
    actS[((gq ^ ((gq >> 3) & 15)) << 2) + ws_] = p2[q * NPIX + pg0 + pxl];
  }
  if (tid < 256)
    ((uint4*)wtS)[tid] = ((const uint4*)(pw2 + zh * 1024))[tid];
  __syncthreads();
  const int pxg = tid & 15, chg = tid >> 4;
  int acc[8][4];
#pragma unroll
  for (int j = 0; j < 8; ++j)
#pragma unroll
    for (int k = 0; k < 4; ++k) acc[j][k] = 0;
#pragma unroll
  for (int q4 = 0; q4 < 2; ++q4) {
    uint4 a[4];
#pragma unroll
    for (int k = 0; k < 4; ++k) {
      int gq = 8 * pxg + 2 * k + q4;
      a[k] = *(const uint4*)&actS[(gq ^ pxg) << 2];
    }
#pragma unroll
    for (int j = 0; j < 8; ++j) {
      uint4 w = *(const uint4*)&wtS[(chg + 16 * j) * 8 + q4 * 4];
#pragma unroll
      for (int k = 0; k < 4; ++k) {
        int t = acc[j][k];
        t += __builtin_popcount(a[k].x ^ w.x);
        t += __builtin_popcount(a[k].y ^ w.y);
        t += __builtin_popcount(a[k].z ^ w.z);
        t += __builtin_popcount(a[k].w ^ w.w);
        acc[j][k] = t;
      }
    }
  }
  const int slot = bx & 63;
#pragma unroll
  for (int j = 0; j < 8; ++j) {
    const int c_l = chg + 16 * j;
    int s[4], sm = 0, sq = 0;
#pragma unroll
    for (int k = 0; k < 4; ++k) {
      s[k] = 256 - 2 * acc[j][k];
      sm += s[k]; sq += s[k] * s[k];
    }
    short4 o4;
    o4.x = (short)s[0]; o4.y = (short)s[1]; o4.z = (short)s[2]; o4.w = (short)s[3];
    *(short4*)&S2[(((size_t)bx * 256) + zh * 128 + c_l) * 64 + pxg * 4] = o4;
#pragma unroll
    for (int m = 1; m < 16; m <<= 1) { sm += __shfl_xor(sm, m, 64); sq += __shfl_xor(sq, m, 64); }
    if (pxg == 0) {
      unsigned long long* st = st2 + ((size_t)(zh * 128 + c_l) * 64 + slot) * 2;
      atomicAdd(&st[0], (unsigned long long)(long long)sm);
      atomicAdd(&st[1], (unsigned long long)(long long)sq);
    }
  }
}

// ============ final: recompute t, BN2 + residual + PReLU chain ============
__global__ __launch_bounds__(256) void final_k(const float* __restrict__ x,
    const short* __restrict__ S1, const short* __restrict__ S2,
    const float* __restrict__ A1, const float* __restrict__ B1,
    const float* __restrict__ b1_2, const float* __restrict__ a1, const float* __restrict__ b1_3,
    const float* __restrict__ A2, const float* __restrict__ B2,
    const float* __restrict__ b2_2, const float* __restrict__ a2, const float* __restrict__ b2_3,
    float* __restrict__ out) {
  const int gi = blockIdx.x * 256 + threadIdx.x;
  const int i4 = gi * 4;
  const int nc = i4 / 3136;
  const int p = i4 - nc * 3136;
  const int n = nc >> 8, c = nc & 255;
  const int h = p / 56, w = p - (p / 56) * 56;
  const int tile = (h >> 3) * 7 + (w >> 3);
  const int px = (h & 7) * 8 + (w & 7);
  short4 s1 = *(const short4*)&S1[(((size_t)n * 49 + tile) * 256 + c) * 64 + px];
  const int pg = n * 3136 + p;
  short4 s2 = *(const short4*)&S2[((size_t)(pg >> 6) * 256 + c) * 64 + (pg & 63)];
  float4 xv = *(const float4*)&x[i4];
  const float A1c = A1[c], B1c = B1[c], P12 = b1_2[c], AL1 = a1[c], P13 = b1_3[c];
  const float A2c = A2[c], B2c = B2[c], P22 = b2_2[c], AL2 = a2[c], P23 = b2_3[c];
  float xs[4] = {xv.x, xv.y, xv.z, xv.w};
  float f1[4] = {(float)s1.x, (float)s1.y, (float)s1.z, (float)s1.w};
  float f2[4] = {(float)s2.x, (float)s2.y, (float)s2.z, (float)s2.w};
  float o[4];
#pragma unroll
  for (int e = 0; e < 4; ++e) {
    float u = xs[e] + (A1c * f1[e] + B1c);
    u = u + P12;
    float v = u >= 0.0f ? u : AL1 * u;
    float t = v + P13;
    float z = (A2c * f2[e] + B2c) + t;
    z = z + P22;
    float vv = z >= 0.0f ? z : AL2 * z;
    o[e] = vv + P23;
  }
  float4 ov = {o[0], o[1], o[2], o[3]};
  *(float4*)&out[i4] = ov;
}

extern "C" void kernel_launch(void* const* d_in, const int* in_sizes, int n_in,
                              void* d_out, int out_size, void* d_ws, size_t ws_size,
                              hipStream_t stream) {
  const float* x    = (const float*)d_in[0];
  const float* b1_1 = (const float*)d_in[1];
  const float* w3x3 = (const float*)d_in[2];
  const float* bn1g = (const float*)d_in[3];
  const float* bn1b = (const float*)d_in[4];
  const float* b1_2 = (const float*)d_in[5];
  const float* a1   = (const float*)d_in[6];
  const float* b1_3 = (const float*)d_in[7];
  const float* b2_1 = (const float*)d_in[8];
  const float* wres = (const float*)d_in[9];
  const float* bn2g = (const float*)d_in[10];
  const float* bn2b = (const float*)d_in[11];
  const float* b2_2 = (const float*)d_in[12];
  const float* a2   = (const float*)d_in[13];
  const float* b2_3 = (const float*)d_in[14];

  char* ws = (char*)d_ws;
  uint32_t* pw2 = (uint32_t*)(ws + OFF_PW2);
  float* sc1 = (float*)(ws + OFF_SC1);
  float* sc2 = (float*)(ws + OFF_SC2);
  float* A1 = (float*)(ws + OFF_A1);
  float* B1 = (float*)(ws + OFF_B1);
  float* A2 = (float*)(ws + OFF_A2);
  float* B2 = (float*)(ws + OFF_B2);
  unsigned long long* st1 = (unsigned long long*)(ws + OFF_ST);
  unsigned long long* st2 = (unsigned long long*)(ws + OFF_ST + 262144u);
  char* wf  = (char*)(ws + OFF_P1);       // W fragments (590KB)
  uint32_t* p2 = (uint32_t*)(ws + OFF_P2);
  short* S1 = (short*)(ws + OFF_S1);
  short* S2 = (short*)(ws + OFF_S2);
  char* act = (char*)(ws + OFF_S2);       // act_i8 aliases S2 (dead before conv2)

  hipMemsetAsync(ws + OFF_ST, 0, ST_BYTES, stream);
  prep_w_k<<<256, 256, 0, stream>>>(w3x3, wres, pw2, sc1, sc2);
  prep_wfrag_k<<<dim3(36, 16), 64, 0, stream>>>(w3x3, wf);
  pack_act_k<<<784, 256, 0, stream>>>(x, b1_1, act);
  conv1_k<<<dim3(49, 32), 256, 0, stream>>>(act, wf, S1, st1);
  bnfin_k<<<256, 64, 0, stream>>>(st1, sc1, bn1g, bn1b, A1, B1);
  pack2_k<<<dim3(98, 8), 256, 0, stream>>>(x, S1, A1, B1, b1_2, a1, b1_3, b2_1, p2);
  conv2_k<<<dim3(1568, 2), 256, 0, stream>>>(p2, pw2, S2, st2);
  bnfin_k<<<256, 64, 0, stream>>>(st2, sc2, bn2g, bn2b, A2, B2);
  final_k<<<25088, 256, 0, stream>>>(x, S1, S2, A1, B1, b1_2, a1, b1_3,
                                     A2, B2, b2_2, a2, b2_3, (float*)d_out);
}